// Round 1
// 229.105 us; speedup vs baseline: 1.0017x; 1.0017x over previous
//
#include <hip/hip_runtime.h>

// LIF neuron scan over STEP=4 timesteps.
// x: [4, 64, 128, 32, 32] fp32; out same shape.
// Per element: mem = mem*0.25 + x_t; spike = mem > 0.5; mem *= (1-spike).
// Forward value of the surrogate activation is the hard threshold.
//
// Pure streaming kernel: 268 MB total traffic -> ~43 us floor at 6.3 TB/s.
// This revision: explicit up-front loads for all 4 timesteps (guaranteed
// memory-level parallelism), nontemporal load/store (touch-once streams,
// evict-first; nt loads still hit L3 if the harness restore left x warm),
// grid-stride with 2048 blocks (8 blocks/CU).

typedef float f4 __attribute__((ext_vector_type(4)));

#define DECAY 0.25f

__device__ __forceinline__ void lif_step(f4& mem, const f4 xv, f4& s) {
    // leaky integrate (mul by 0.25 is exact; fma contraction is bit-identical)
    mem = mem * DECAY + xv;
    // fire (V_TH = 1.0, so v == mem)
    s.x = mem.x > 0.5f ? 1.f : 0.f;
    s.y = mem.y > 0.5f ? 1.f : 0.f;
    s.z = mem.z > 0.5f ? 1.f : 0.f;
    s.w = mem.w > 0.5f ? 1.f : 0.f;
    // reset where spiked
    mem.x = (s.x != 0.f) ? 0.f : mem.x;
    mem.y = (s.y != 0.f) ? 0.f : mem.y;
    mem.z = (s.z != 0.f) ? 0.f : mem.z;
    mem.w = (s.w != 0.f) ? 0.f : mem.w;
}

__global__ __launch_bounds__(256) void lif_kernel(const f4* __restrict__ x,
                                                  f4* __restrict__ out,
                                                  int n4) {
    const int tid = blockIdx.x * blockDim.x + threadIdx.x;
    const int T = gridDim.x * blockDim.x;

    for (int i = tid; i < n4; i += T) {
        const size_t i0 = (size_t)i;
        const size_t i1 = (size_t)n4 + i;
        const size_t i2 = 2 * (size_t)n4 + i;
        const size_t i3 = 3 * (size_t)n4 + i;

        // all 4 timestep loads in flight before the dependent scan chain
        f4 x0 = __builtin_nontemporal_load(x + i0);
        f4 x1 = __builtin_nontemporal_load(x + i1);
        f4 x2 = __builtin_nontemporal_load(x + i2);
        f4 x3 = __builtin_nontemporal_load(x + i3);

        f4 mem = {0.f, 0.f, 0.f, 0.f};
        f4 s0, s1, s2, s3;
        lif_step(mem, x0, s0);
        lif_step(mem, x1, s1);
        lif_step(mem, x2, s2);
        lif_step(mem, x3, s3);

        __builtin_nontemporal_store(s0, out + i0);
        __builtin_nontemporal_store(s1, out + i1);
        __builtin_nontemporal_store(s2, out + i2);
        __builtin_nontemporal_store(s3, out + i3);
    }
}

extern "C" void kernel_launch(void* const* d_in, const int* in_sizes, int n_in,
                              void* d_out, int out_size, void* d_ws, size_t ws_size,
                              hipStream_t stream) {
    const float* x = (const float*)d_in[0];
    float* out = (float*)d_out;

    int n = in_sizes[0];       // 4 * 64 * 128 * 32 * 32 = 33,554,432
    int n4 = n / 16;           // float4 granules per timestep = 2,097,152

    const int block = 256;
    int grid = 2048;           // 8 blocks/CU on 256 CUs; grid-stride covers n4
    int max_grid = (n4 + block - 1) / block;
    if (grid > max_grid) grid = max_grid;

    lif_kernel<<<grid, block, 0, stream>>>((const f4*)x, (f4*)out, n4);
}